// Round 5
// baseline (268.284 us; speedup 1.0000x reference)
//
#include <hip/hip_runtime.h>

// DiffTreeInterpreter: row-pair CSR gather, guarded-issue edition.
//
// Output row r (batch b):
//   half: r<2048: car from role 2r (scale op0*w0), cdr from role 2r+1>=3 (op1*w1)
//   cons: all r: from role r>>1 (scale op2*w2 if r even else op2*w3)
//   root: out[b,1,:] += op2*root_filler[b]
// One wave handles the row PAIR (2q, 2q+1): cons tokens (role q) are shared ->
// one mem-row load feeds both rows. Counts are wave-uniform -> validity guards
// are scalar branches (skipped load = ~2 cyc, issued load = 4 L1 transactions).
// pad-masking in the reference is a numeric no-op (padded rows are all-zero).

namespace {
constexpr int kB = 32;
constexpr int kL = 128;
constexpr int kF = 128;
constexpr int kR = 4096;
constexpr int kN = 262144;
constexpr int kQ = 2048;       // row-pairs per batch == half-rows per batch
constexpr int kNP = kB * kQ;   // 65536 keys
constexpr int kCap = 16;       // entries per record; P(Poisson(4)>16)~4e-7
constexpr int kOvfMax = 65536;

// workspace layout (bytes)
constexpr size_t kOffRowCnt  = 0;        // kNP*4  = 262144
constexpr size_t kOffConsCnt = 262144;   // kNP*4  = 262144
constexpr size_t kOffOvfCnt  = 524288;   // 4 (pad 16)
constexpr size_t kOffOvf     = 524304;   // kOvfMax*16 = 1048576
constexpr size_t kOffRowEnt  = 1572880;  // kNP*kCap*8  = 8388608  (int2)
constexpr size_t kOffConsEnt = 9961488;  // kNP*kCap*16 = 16777216 (int4)
// end: 26,738,704 bytes (~25.5 MB)
}  // namespace

__global__ __launch_bounds__(256) void build_kernel(
    const float4* __restrict__ aw, const float* __restrict__ opd,
    const int* __restrict__ bidx, const int* __restrict__ sidx,
    const int* __restrict__ ridx,
    int* __restrict__ rowcnt, int* __restrict__ conscnt,
    int* __restrict__ ovf_cnt, int4* __restrict__ ovf,
    int2* __restrict__ rowent, int4* __restrict__ consent) {
  int n = blockIdx.x * 256 + threadIdx.x;
  if (n >= kN) return;
  int b = bidx[n];
  int s = sidx[n];
  int rr = ridx[n];
  float4 w = aw[b * kL + s];
  float op0 = opd[3 * b + 0];
  float op1 = opd[3 * b + 1];
  float op2 = opd[3 * b + 2];

  // half contribution -> row rr>>1 (car if even, cdr if odd>=3; role 1 dropped)
  bool even = (rr & 1) == 0;
  if (even || rr >= 3) {
    float sc = even ? op0 * w.x : op1 * w.y;
    int key = (b << 11) | (rr >> 1);
    int pos = atomicAdd(&rowcnt[key], 1);
    if (pos < kCap) {
      rowent[key * kCap + pos] = make_int2(n, __float_as_int(sc));
    } else {
      int o = atomicAdd(ovf_cnt, 1);
      if (o < kOvfMax)
        ovf[o] = make_int4(b * kR + (rr >> 1), n, __float_as_int(sc), 0);
    }
  }
  // cons contribution -> rows 2rr, 2rr+1 : ONE entry (n, s1, s2)
  if (rr < kQ) {
    int key = (b << 11) | rr;
    int pos = atomicAdd(&conscnt[key], 1);
    if (pos < kCap) {
      consent[key * kCap + pos] =
          make_int4(n, __float_as_int(op2 * w.z), __float_as_int(op2 * w.w), 0);
    } else {
      int o = atomicAdd(ovf_cnt, 2);
      if (o < kOvfMax)
        ovf[o] = make_int4(b * kR + 2 * rr, n, __float_as_int(op2 * w.z), 0);
      if (o + 1 < kOvfMax)
        ovf[o + 1] =
            make_int4(b * kR + 2 * rr + 1, n, __float_as_int(op2 * w.w), 0);
    }
  }
}

__global__ __launch_bounds__(256) void gather_kernel(
    const float2* __restrict__ mem2, const float2* __restrict__ root2,
    const float* __restrict__ opd,
    const int* __restrict__ rowcnt, const int* __restrict__ conscnt,
    const int2* __restrict__ rowent, const int2* __restrict__ consent2,
    float2* __restrict__ out2) {
  const int p = blockIdx.x * 4 + (threadIdx.x >> 6);  // pair id = (b<<11)|q
  const int t = threadIdx.x & 63;                     // lane: features 2t,2t+1
  const int b = p >> 11;
  const int q = p & (kQ - 1);
  const bool hashalf = q < 1024;  // rows 2q,2q+1 < 2048

  // ---- round 1: ALL structure loads, fully independent ----
  int cn_raw = conscnt[p];
  int2 ce = make_int2(0, 0);
  if (t < 32) ce = (consent2 + (size_t)p * 2 * kCap)[t];  // 16 int4 = 32 int2
  int2 hc = make_int2(0, 0);
  int2 he = make_int2(0, 0);
  if (hashalf) {
    int key0 = (b << 11) | (q << 1);            // even -> 8B aligned
    hc = *(const int2*)(rowcnt + key0);         // counts for rows 2q, 2q+1
    if (t < 32) he = (rowent + (size_t)key0 * kCap)[t];  // both records, 256B
  }
  const int cn = min(__builtin_amdgcn_readfirstlane(cn_raw), kCap);
  const int h0 = hashalf ? min(__builtin_amdgcn_readfirstlane(hc.x), kCap) : 0;
  const int h1 = hashalf ? min(__builtin_amdgcn_readfirstlane(hc.y), kCap) : 0;

  // ---- round 2: guarded issue (counts are wave-uniform -> scalar branches;
  //      only valid slots issue loads, all issued loads are independent) ----
  float2 mc[4];
  float c1s[4], c2s[4];
#pragma unroll
  for (int j = 0; j < 4; ++j) {
    int nn = __shfl(ce.x, 2 * j);
    float a = __int_as_float(__shfl(ce.y, 2 * j));
    float bb = __int_as_float(__shfl(ce.x, 2 * j + 1));
    bool v = j < cn;  // uniform
    c1s[j] = v ? a : 0.f;  // slots >= cn hold 0xAA poison -> zero the scale
    c2s[j] = v ? bb : 0.f;
    mc[j] = make_float2(0.f, 0.f);
    if (v) mc[j] = mem2[(size_t)nn * (kF / 2) + t];
  }
  float2 m0[8], m1[8];
  float s0a[8], s1a[8];
#pragma unroll
  for (int j = 0; j < 8; ++j) {
    int nn = __shfl(he.x, j);
    float s = __int_as_float(__shfl(he.y, j));
    bool v = j < h0;  // uniform
    s0a[j] = v ? s : 0.f;
    m0[j] = make_float2(0.f, 0.f);
    if (v) m0[j] = mem2[(size_t)nn * (kF / 2) + t];
  }
#pragma unroll
  for (int j = 0; j < 8; ++j) {
    int nn = __shfl(he.x, 16 + j);
    float s = __int_as_float(__shfl(he.y, 16 + j));
    bool v = j < h1;  // uniform
    s1a[j] = v ? s : 0.f;
    m1[j] = make_float2(0.f, 0.f);
    if (v) m1[j] = mem2[(size_t)nn * (kF / 2) + t];
  }

  // ---- accumulate ----
  float ax0 = 0.f, ay0 = 0.f, ax1 = 0.f, ay1 = 0.f;
#pragma unroll
  for (int j = 0; j < 4; ++j) {
    ax0 += c1s[j] * mc[j].x;
    ay0 += c1s[j] * mc[j].y;
    ax1 += c2s[j] * mc[j].x;
    ay1 += c2s[j] * mc[j].y;
  }
#pragma unroll
  for (int j = 0; j < 8; ++j) {
    ax0 += s0a[j] * m0[j].x;
    ay0 += s0a[j] * m0[j].y;
    ax1 += s1a[j] * m1[j].x;
    ay1 += s1a[j] * m1[j].y;
  }

  // ---- rare tails (P(Poisson(2)>4)~5% cons, P(Poisson(4)>8)~2% halves) ----
  for (int i = 4; i < cn; ++i) {
    int nn = __shfl(ce.x, 2 * i);
    float a = __int_as_float(__shfl(ce.y, 2 * i));
    float bb = __int_as_float(__shfl(ce.x, 2 * i + 1));
    float2 m = mem2[(size_t)nn * (kF / 2) + t];
    ax0 += a * m.x;
    ay0 += a * m.y;
    ax1 += bb * m.x;
    ay1 += bb * m.y;
  }
  for (int i = 8; i < h0; ++i) {
    int nn = __shfl(he.x, i);
    float s = __int_as_float(__shfl(he.y, i));
    float2 m = mem2[(size_t)nn * (kF / 2) + t];
    ax0 += s * m.x;
    ay0 += s * m.y;
  }
  for (int i = 8; i < h1; ++i) {
    int nn = __shfl(he.x, 16 + i);
    float s = __int_as_float(__shfl(he.y, 16 + i));
    float2 m = mem2[(size_t)nn * (kF / 2) + t];
    ax1 += s * m.x;
    ay1 += s * m.y;
  }

  // ---- root filler (row 1 <=> q==0) + writeback ----
  if (q == 0) {
    float op2 = opd[3 * b + 2];
    float2 rf = root2[b * (kF / 2) + t];
    ax1 += op2 * rf.x;
    ay1 += op2 * rf.y;
  }
  size_t orow = ((size_t)b * kR + 2 * q) * (kF / 2) + t;
  out2[orow] = make_float2(ax0, ay0);
  out2[orow + (kF / 2)] = make_float2(ax1, ay1);
}

// Overflow fallback (expected ~0 entries): direct atomic add.
// Must run AFTER gather_kernel (gather writes out with '=').
__global__ __launch_bounds__(128) void ovf_kernel(
    const float* __restrict__ mem, const int* __restrict__ ovf_cnt,
    const int4* __restrict__ ovf, float* __restrict__ out) {
  int m = *ovf_cnt;
  if (m > kOvfMax) m = kOvfMax;
  const int t = threadIdx.x;  // feature 0..127
  for (int i = blockIdx.x; i < m; i += gridDim.x) {
    int4 e = ovf[i];
    float sc = __int_as_float(e.z);
    atomicAdd(&out[(size_t)e.x * kF + t], sc * mem[(size_t)e.y * kF + t]);
  }
}

extern "C" void kernel_launch(void* const* d_in, const int* in_sizes, int n_in,
                              void* d_out, int out_size, void* d_ws, size_t ws_size,
                              hipStream_t stream) {
  const float* mem   = (const float*)d_in[0];   // (N, F)
  const float* aw    = (const float*)d_in[1];   // (B, L, 4)
  const float* rootf = (const float*)d_in[2];   // (B, F)
  const float* opd   = (const float*)d_in[3];   // (B, 3)
  const int* bidx    = (const int*)d_in[4];     // (N,)
  const int* sidx    = (const int*)d_in[5];     // (N,)
  const int* ridx    = (const int*)d_in[6];     // (N,)

  char* ws = (char*)d_ws;
  int* rowcnt   = (int*)(ws + kOffRowCnt);
  int* conscnt  = (int*)(ws + kOffConsCnt);
  int* ovf_cnt  = (int*)(ws + kOffOvfCnt);
  int4* ovf     = (int4*)(ws + kOffOvf);
  int2* rowent  = (int2*)(ws + kOffRowEnt);
  int4* consent = (int4*)(ws + kOffConsEnt);

  // zero all counters in one contiguous memset (ws is poisoned 0xAA each call)
  hipMemsetAsync(ws, 0, kOffOvfCnt + 16, stream);

  build_kernel<<<kN / 256, 256, 0, stream>>>(
      (const float4*)aw, opd, bidx, sidx, ridx, rowcnt, conscnt, ovf_cnt, ovf,
      rowent, consent);

  gather_kernel<<<kNP / 4, 256, 0, stream>>>(
      (const float2*)mem, (const float2*)rootf, opd, rowcnt, conscnt, rowent,
      (const int2*)consent, (float2*)d_out);

  ovf_kernel<<<64, 128, 0, stream>>>(mem, ovf_cnt, ovf, (float*)d_out);
}